// Round 2
// baseline (522.522 us; speedup 1.0000x reference)
//
#include <hip/hip_runtime.h>

// ---------------------------------------------------------------------------
// BitfieldLinear via rank-structure split:
//   y = r_n * P[m, c_n] + (a_m * s_n/127) * (xq @ qb^T) + bias
//   P = x @ basis^T  (bf16 MFMA, stored bf16 [M,256])
// R6: gemm_i8 ported to the 256x256 8-phase counted-vmcnt template
//     (BK=128, K-half staging, T3+T4+T5; T2 swizzle carried over).
//     p_gemm: 512 threads (2 waves/SIMD) + 2-phase double-buffer prefetch.
// R7: identical resubmit (R6 bench died to container infra, no counters).
// ---------------------------------------------------------------------------

typedef __bf16 bf16x8 __attribute__((ext_vector_type(8)));
typedef float f32x4 __attribute__((ext_vector_type(4)));
typedef int i32x4 __attribute__((ext_vector_type(4)));
typedef unsigned short u16x8 __attribute__((ext_vector_type(8)));

__device__ __forceinline__ unsigned short f2bf(float f) {
    union { float f; unsigned int u; } c; c.f = f;
    unsigned int u = c.u;
    u += 0x7fffu + ((u >> 16) & 1u);
    return (unsigned short)(u >> 16);
}
__device__ __forceinline__ float bf2f(unsigned short h) {
    union { unsigned int u; float f; } c; c.u = ((unsigned int)h) << 16;
    return c.f;
}

__device__ __forceinline__ void load_lds16(const void* g, void* l) {
    __builtin_amdgcn_global_load_lds(
        (__attribute__((address_space(1))) void*)(void*)g,
        (__attribute__((address_space(3))) void*)l,
        16, 0, 0);
}

// r4-verified swizzle for 64-B-row tiles (0 conflicts measured):
// physical 16B-slot p -> (row, chunk) byte offset; 8-slot groups span 2 rows.
__device__ __forceinline__ int swz_decode(int p, int row_bytes) {
    const int g = p >> 3, t = p & 7, v = t ^ (g & 7);
    const int row = g * 2 + (v >> 2), chunk = v & 3;
    return row * row_bytes + chunk * 16;
}

// ---------------- basis fp32 -> bf16 ---------------------------------------
__global__ void cvt_bf16_kernel(const float4* __restrict__ in4,
                                ushort4* __restrict__ out4, int n4) {
    int i = blockIdx.x * blockDim.x + threadIdx.x;
    const int stride = gridDim.x * blockDim.x;
    for (; i < n4; i += stride) {
        float4 v = in4[i];
        ushort4 o;
        o.x = f2bf(v.x); o.y = f2bf(v.y); o.z = f2bf(v.z); o.w = f2bf(v.w);
        out4[i] = o;
    }
}

// ---------------- per-row int8 quantization of x ---------------------------
__global__ void quant_x_kernel(const float* __restrict__ x,
                               signed char* __restrict__ xq,
                               float* __restrict__ arow, int K) {
    const int m = blockIdx.x;
    const float* row = x + (size_t)m * K;
    const int base = threadIdx.x * 16;
    float4 v[4];
#pragma unroll
    for (int j = 0; j < 4; ++j) v[j] = *(const float4*)(row + base + j * 4);

    float lmax = 0.f;
#pragma unroll
    for (int j = 0; j < 4; ++j) {
        lmax = fmaxf(lmax, fabsf(v[j].x));
        lmax = fmaxf(lmax, fabsf(v[j].y));
        lmax = fmaxf(lmax, fabsf(v[j].z));
        lmax = fmaxf(lmax, fabsf(v[j].w));
    }
#pragma unroll
    for (int off = 32; off; off >>= 1)
        lmax = fmaxf(lmax, __shfl_xor(lmax, off));
    __shared__ float smax[4];
    if ((threadIdx.x & 63) == 0) smax[threadIdx.x >> 6] = lmax;
    __syncthreads();
    const float mx = fmaxf(fmaxf(smax[0], smax[1]), fmaxf(smax[2], smax[3]));
    const float inv = mx > 0.f ? 127.0f / mx : 0.0f;
    if (threadIdx.x == 0) arow[m] = mx * (1.0f / 127.0f);

    union { signed char c[16]; i32x4 w; } pk;
#pragma unroll
    for (int j = 0; j < 4; ++j) {
        pk.c[j * 4 + 0] = (signed char)(int)rintf(v[j].x * inv);
        pk.c[j * 4 + 1] = (signed char)(int)rintf(v[j].y * inv);
        pk.c[j * 4 + 2] = (signed char)(int)rintf(v[j].z * inv);
        pk.c[j * 4 + 3] = (signed char)(int)rintf(v[j].w * inv);
    }
    *(i32x4*)(xq + (size_t)m * K + base) = pk.w;
}

// ---------------- pack residual int32 -> int8 (q-128) ----------------------
__global__ void pack_q_kernel(const int4* __restrict__ q4,
                              unsigned int* __restrict__ out, int n4) {
    const int i = blockIdx.x * blockDim.x + threadIdx.x;
    if (i >= n4) return;
    int4 a = q4[i];
    unsigned int w = ((unsigned)(a.x - 128) & 0xFFu)
                   | (((unsigned)(a.y - 128) & 0xFFu) << 8)
                   | (((unsigned)(a.z - 128) & 0xFFu) << 16)
                   | (((unsigned)(a.w - 128) & 0xFFu) << 24);
    out[i] = w;
}

// ---------------- P = x @ basis^T, bf16 out --------------------------------
// Tile: 32 rows (M) x 256 cols (ALL of basis), BK=64. 256 blocks (M/32).
// 512 threads (8 waves, wave = 16 rows x 64 cols), double-buffered
// staging with counted vmcnt(5) so next tile's HBM latency hides under MFMA.
__global__ __launch_bounds__(512) void
p_gemm_kernel(const float* __restrict__ x,           // [M,K] fp32
              const unsigned short* __restrict__ Bb, // [256,K] bf16
              unsigned short* __restrict__ Pbf,      // [M,256] bf16
              int M, int K) {
    __shared__ __align__(16) float As[2][32 * 64];            // 2 x 8 KB
    __shared__ __align__(16) unsigned short Bs[2][256 * 64];  // 2 x 32 KB

    const int tid  = threadIdx.x;
    const int lane = tid & 63;
    const int wv   = tid >> 6;        // 0..7
    const int wr   = wv >> 2;         // 0..1: row half (16 rows)
    const int wc   = wv & 3;          // 0..3: 64-col group
    const int m0 = blockIdx.x * 32;
    const int lr = lane & 15;
    const int kg = lane >> 4;

    f32x4 acc[4];
#pragma unroll
    for (int ni = 0; ni < 4; ++ni) acc[ni] = (f32x4){0.f, 0.f, 0.f, 0.f};

    // A staging: 512 slots (32 rows x 16 chunks of 4 fp32), 1/thread.
    const int aRow = tid >> 4;
    const int aSrc = (tid & 15) ^ (aRow & 15);
    // B staging: 2048 slots (256 rows x 8 chunks of 8 bf16), 4/thread.
    int bRow[4], bSrc[4];
#pragma unroll
    for (int j = 0; j < 4; ++j) {
        const int p = tid + 512 * j;
        bRow[j] = p >> 3;
        bSrc[j] = (p & 7) ^ (bRow[j] & 7);
    }
    const float* aG = x + (size_t)(m0 + aRow) * K + aSrc * 4;
    const unsigned short* bG[4];
#pragma unroll
    for (int j = 0; j < 4; ++j) bG[j] = Bb + (size_t)bRow[j] * K + bSrc[j] * 8;

#define P_STAGE(bb, k0)                                                        \
    do {                                                                       \
        load_lds16(aG + (k0), (char*)As[bb] + tid * 16);                       \
        _Pragma("unroll") for (int j = 0; j < 4; ++j)                          \
            load_lds16(bG[j] + (k0), (char*)Bs[bb] + (tid + 512 * j) * 16);    \
    } while (0)

    P_STAGE(0, 0);
    const int NT = K >> 6;
    for (int t = 0; t < NT; ++t) {
        const int bb = t & 1;
        if (t + 1 < NT) {
            P_STAGE(bb ^ 1, (t + 1) << 6);
            asm volatile("s_waitcnt vmcnt(5)" ::: "memory");  // tile t resident
        } else {
            asm volatile("s_waitcnt vmcnt(0)" ::: "memory");
        }
        __builtin_amdgcn_s_barrier();

        const float* Ab = As[bb];
        const unsigned short* Bbf = Bs[bb];
#pragma unroll
        for (int s = 0; s < 2; ++s) {
            const int r = wr * 16 + lr;
            const int c0 = s * 8 + kg * 2;
            const int ph0 = c0 ^ (r & 15);
            const int ph1 = (c0 + 1) ^ (r & 15);
            f32x4 lo = *(const f32x4*)(Ab + r * 64 + ph0 * 4);
            f32x4 hi = *(const f32x4*)(Ab + r * 64 + ph1 * 4);
            bf16x8 a;
            a[0] = (__bf16)lo[0]; a[1] = (__bf16)lo[1];
            a[2] = (__bf16)lo[2]; a[3] = (__bf16)lo[3];
            a[4] = (__bf16)hi[0]; a[5] = (__bf16)hi[1];
            a[6] = (__bf16)hi[2]; a[7] = (__bf16)hi[3];
#pragma unroll
            for (int ni = 0; ni < 4; ++ni) {
                const int rb = wc * 64 + ni * 16 + lr;
                const int ph = (s * 4 + kg) ^ (rb & 7);
                bf16x8 bfr = __builtin_bit_cast(bf16x8,
                    *(const u16x8*)(Bbf + rb * 64 + ph * 8));
                acc[ni] = __builtin_amdgcn_mfma_f32_16x16x32_bf16(
                    a, bfr, acc[ni], 0, 0, 0);
            }
        }
        __builtin_amdgcn_s_barrier();
    }
#undef P_STAGE

#pragma unroll
    for (int ni = 0; ni < 4; ++ni) {
        const int n = wc * 64 + ni * 16 + lr;
        const int mb = m0 + wr * 16 + kg * 4;
#pragma unroll
        for (int rg = 0; rg < 4; ++rg)
            Pbf[(size_t)(mb + rg) * 256 + n] = f2bf(acc[ni][rg]);
    }
}

// ---------------- main i8 GEMM + fused epilogue ----------------------------
// 256(M) x 256(N) tile, BK=128, 8 waves (2Mx4N, wave = 128 x 64).
// 8-phase counted-vmcnt schedule: per K-tile 4 phases (K-half x N-half
// quadrant, 16 MFMA each), one 16KB half-tile staged per phase
// (2 x global_load_lds/thread), vmcnt(4) only at phases 2 & 4,
// s_setprio around MFMA clusters. LDS: 2 dbuf x (A[2ks][256x64] +
// B[2ks][256x64]) = 128 KB, each sub-region keeps the r4-verified swizzle.
__global__ __launch_bounds__(512, 2) void
gemm_i8_kernel(const signed char* __restrict__ Xq, // [M,K]
               const signed char* __restrict__ Qb, // [N,K]
               const float* __restrict__ arow,     // [M]
               const int* __restrict__ codes,      // [N]
               const float* __restrict__ scales,   // [N]
               const float* __restrict__ bias,     // [N]
               const unsigned short* __restrict__ Pbf, // [M,256] bf16
               float* __restrict__ out,            // [M,N]
               int M, int N, int K) {
    __shared__ __align__(16) signed char lds[2 * 65536];  // 128 KB

    const int tid  = threadIdx.x;
    const int lane = tid & 63;
    const int wv   = tid >> 6;
    const int wr   = wv >> 2;         // 0..1 (128-row half)
    const int wc   = wv & 3;          // 0..3 (64-col quarter)
    const int m0 = blockIdx.x * 256;
    const int n0 = blockIdx.y * 256;
    const int lr = lane & 15;
    const int kg = lane >> 4;
    const int cidx = (((lr & 1) << 2) | kg) ^ ((lr >> 1) & 7);

    // staging: each 16KB sub-region = 1024 slots of 16B (256 rows x 64B).
    // Thread covers slots tid and tid+512; source pre-swizzled (r4 pattern).
    const int o0 = swz_decode(tid, 64);
    const int o1 = swz_decode(tid + 512, 64);
    const signed char* aG0 = Xq + (size_t)(m0 + (o0 >> 6)) * K + (o0 & 63);
    const signed char* aG1 = Xq + (size_t)(m0 + (o1 >> 6)) * K + (o1 & 63);
    const signed char* bG0 = Qb + (size_t)(n0 + (o0 >> 6)) * K + (o0 & 63);
    const signed char* bG1 = Qb + (size_t)(n0 + (o1 >> 6)) * K + (o1 & 63);
    const int d0 = tid * 16;
    const int d1 = d0 + 8192;

    i32x4 acc[8][4];
#pragma unroll
    for (int mi = 0; mi < 8; ++mi)
#pragma unroll
        for (int ni = 0; ni < 4; ++ni)
            acc[mi][ni] = (i32x4){0, 0, 0, 0};

    // LDS fragment read bases (verified-conflict-free pattern, re-based):
    // A frag (mi,ks): buf + ks*16384 + raBase + mi*1024
    // B frag (ni,ks): buf + ks*16384 + rbBase + ni*1024   (rbBase incl +32768)
    const int raBase = (wr * 64 + (lr >> 1)) * 128 + cidx * 16;
    const int rbBase = 32768 + (wc * 32 + (lr >> 1)) * 128 + cidx * 16;

#define STG_A(bufo, ks, kb)                                                    \
    do {                                                                       \
        load_lds16(aG0 + (kb) + (ks) * 64, lds + (bufo) + (ks) * 16384 + d0);  \
        load_lds16(aG1 + (kb) + (ks) * 64, lds + (bufo) + (ks) * 16384 + d1);  \
    } while (0)
#define STG_B(bufo, ks, kb)                                                    \
    do {                                                                       \
        load_lds16(bG0 + (kb) + (ks) * 64,                                     \
                   lds + (bufo) + 32768 + (ks) * 16384 + d0);                  \
        load_lds16(bG1 + (kb) + (ks) * 64,                                     \
                   lds + (bufo) + 32768 + (ks) * 16384 + d1);                  \
    } while (0)

    // Prologue: stage tile 0 fully (8 loads); wait for its ks0 halves only.
    STG_A(0, 0, 0); STG_B(0, 0, 0); STG_A(0, 1, 0); STG_B(0, 1, 0);
    asm volatile("s_waitcnt vmcnt(4)" ::: "memory");
    __builtin_amdgcn_s_barrier();

    const int NT = K >> 7;  // BK=128
#pragma unroll 2
    for (int t = 0; t < NT; ++t) {
        const int buf  = (t & 1) << 16;
        const int nbuf = buf ^ 65536;
        const int kb   = (t + 1) << 7;
        const bool pre = (t + 1) < NT;
        i32x4 a[8], b0, b1;

        // ---- phase 1: ks0, ni {0,1} ----
#pragma unroll
        for (int mi = 0; mi < 8; ++mi)
            a[mi] = *(const i32x4*)(lds + buf + raBase + mi * 1024);
        b0 = *(const i32x4*)(lds + buf + rbBase + 0 * 1024);
        b1 = *(const i32x4*)(lds + buf + rbBase + 1 * 1024);
        if (pre) STG_A(nbuf, 0, kb);
        __builtin_amdgcn_s_barrier();
        asm volatile("s_waitcnt lgkmcnt(0)" ::: "memory");
        __builtin_amdgcn_s_setprio(1);
#pragma unroll
        for (int mi = 0; mi < 8; ++mi)
            acc[mi][0] = __builtin_amdgcn_mfma_i32_16x16x64_i8(a[mi], b0,
                                                               acc[mi][0], 0, 0, 0);
#pragma unroll
        for (int mi = 0; mi < 8; ++mi)
            acc[mi][1] = __builtin_amdgcn_mfma_i32_16x16x64_i8(a[mi], b1,
                                                               acc[mi][1], 0, 0, 0);
        __builtin_amdgcn_s_setprio(0);
        __builtin_amdgcn_s_barrier();

        // ---- phase 2: ks0, ni {2,3} (A held in regs) ----
        b0 = *(const i32x4*)(lds + buf + rbBase + 2 * 1024);
        b1 = *(const i32x4*)(lds + buf + rbBase + 3 * 1024);
        if (pre) STG_B(nbuf, 0, kb);
        __builtin_amdgcn_s_barrier();
        asm volatile("s_waitcnt lgkmcnt(0)" ::: "memory");
        __builtin_amdgcn_s_setprio(1);
#pragma unroll
        for (int mi = 0; mi < 8; ++mi)
            acc[mi][2] = __builtin_amdgcn_mfma_i32_16x16x64_i8(a[mi], b0,
                                                               acc[mi][2], 0, 0, 0);
#pragma unroll
        for (int mi = 0; mi < 8; ++mi)
            acc[mi][3] = __builtin_amdgcn_mfma_i32_16x16x64_i8(a[mi], b1,
                                                               acc[mi][3], 0, 0, 0);
        __builtin_amdgcn_s_setprio(0);
        if (pre) asm volatile("s_waitcnt vmcnt(4)" ::: "memory");  // this tile ks1 in
        else     asm volatile("s_waitcnt vmcnt(0)" ::: "memory");
        __builtin_amdgcn_s_barrier();

        // ---- phase 3: ks1, ni {0,1} ----
#pragma unroll
        for (int mi = 0; mi < 8; ++mi)
            a[mi] = *(const i32x4*)(lds + buf + 16384 + raBase + mi * 1024);
        b0 = *(const i32x4*)(lds + buf + 16384 + rbBase + 0 * 1024);
        b1 = *(const i32x4*)(lds + buf + 16384 + rbBase + 1 * 1024);
        if (pre) STG_A(nbuf, 1, kb);
        __builtin_amdgcn_s_barrier();
        asm volatile("s_waitcnt lgkmcnt(0)" ::: "memory");
        __builtin_amdgcn_s_setprio(1);
#pragma unroll
        for (int mi = 0; mi < 8; ++mi)
            acc[mi][0] = __builtin_amdgcn_mfma_i32_16x16x64_i8(a[mi], b0,
                                                               acc[mi][0], 0, 0, 0);
#pragma unroll
        for (int mi = 0; mi < 8; ++mi)
            acc[mi][1] = __builtin_amdgcn_mfma_i32_16x16x64_i8(a[mi], b1,
                                                               acc[mi][1], 0, 0, 0);
        __builtin_amdgcn_s_setprio(0);
        __builtin_amdgcn_s_barrier();

        // ---- phase 4: ks1, ni {2,3} ----
        b0 = *(const i32x4*)(lds + buf + 16384 + rbBase + 2 * 1024);
        b1 = *(const i32x4*)(lds + buf + 16384 + rbBase + 3 * 1024);
        if (pre) STG_B(nbuf, 1, kb);
        __builtin_amdgcn_s_barrier();
        asm volatile("s_waitcnt lgkmcnt(0)" ::: "memory");
        __builtin_amdgcn_s_setprio(1);
#pragma unroll
        for (int mi = 0; mi < 8; ++mi)
            acc[mi][2] = __builtin_amdgcn_mfma_i32_16x16x64_i8(a[mi], b0,
                                                               acc[mi][2], 0, 0, 0);
#pragma unroll
        for (int mi = 0; mi < 8; ++mi)
            acc[mi][3] = __builtin_amdgcn_mfma_i32_16x16x64_i8(a[mi], b1,
                                                               acc[mi][3], 0, 0, 0);
        __builtin_amdgcn_s_setprio(0);
        if (pre) asm volatile("s_waitcnt vmcnt(4)" ::: "memory");  // next ks0 in
        __builtin_amdgcn_s_barrier();
    }
#undef STG_A
#undef STG_B

    // ---- epilogue: per-row x scales, per-col decode, P gather, NT store ---
    const int mwb = m0 + wr * 128 + kg * 4;
    float av[8][4];
#pragma unroll
    for (int mi = 0; mi < 8; ++mi)
#pragma unroll
        for (int rg = 0; rg < 4; ++rg)
            av[mi][rg] = arow[mwb + mi * 16 + rg];

#pragma unroll
    for (int ni = 0; ni < 4; ++ni) {
        const int n = n0 + wc * 64 + ni * 16 + lr;
        const int code = codes[n];
        const int cc = code & 0xFF;
        const float rr = (float)((code >> 8) & 0xFFFF) * (1.0f / 65535.0f);
        const float so = scales[n] * (1.0f / 127.0f);
        const float bv = bias[n];
#pragma unroll
        for (int mi = 0; mi < 8; ++mi) {
            const int mbase = mwb + mi * 16;
            unsigned short pv[4];
#pragma unroll
            for (int rg = 0; rg < 4; ++rg)
                pv[rg] = Pbf[(size_t)(mbase + rg) * 256 + cc];
#pragma unroll
            for (int rg = 0; rg < 4; ++rg) {
                const float y = av[mi][rg] * so * (float)acc[mi][ni][rg]
                              + rr * bf2f(pv[rg]) + bv;
                __builtin_nontemporal_store(y, &out[(size_t)(mbase + rg) * N + n]);
            }
        }
    }
}

// ---------------------------------------------------------------------------
extern "C" void kernel_launch(void* const* d_in, const int* in_sizes, int n_in,
                              void* d_out, int out_size, void* d_ws, size_t ws_size,
                              hipStream_t stream) {
    const float* x        = (const float*)d_in[0];
    const int*   codes    = (const int*)d_in[1];
    const float* basis    = (const float*)d_in[2];
    const int*   q        = (const int*)d_in[3];
    const float* scales   = (const float*)d_in[4];
    const float* bias     = (const float*)d_in[5];
    float* out = (float*)d_out;

    const int BASIS = 256;
    const int K = in_sizes[2] / BASIS;   // 4096
    const int N = in_sizes[1];           // 4096
    const int M = in_sizes[0] / K;       // 8192

    char* ws = (char*)d_ws;
    signed char* Xq = (signed char*)ws;                  // [M,K] i8, 33.5 MB
    size_t off = (size_t)M * K;
    signed char* Qb = (signed char*)(ws + off);          // [N,K] i8, 16.7 MB
    off += (size_t)N * K;
    unsigned short* Pbf = (unsigned short*)(ws + off);   // [M,256] bf16, 4 MB
    off += (size_t)M * 256 * 2;
    float* Arow = (float*)(ws + off);                    // [M] fp32
    off += (size_t)M * sizeof(float);
    unsigned short* Bb = (unsigned short*)(ws + off);    // [256,K] bf16, 2 MB

    // 1. basis -> bf16 (2 MB)
    cvt_bf16_kernel<<<1024, 256, 0, stream>>>((const float4*)basis, (ushort4*)Bb,
                                              BASIS * K / 4);
    // 2. P = x @ basis^T  (reads x fp32 directly)
    p_gemm_kernel<<<M / 32, 512, 0, stream>>>(x, Bb, Pbf, M, K);
    // 3. x -> i8 + per-row scale
    quant_x_kernel<<<M, 256, 0, stream>>>(x, Xq, Arow, K);
    // 4. residual -> i8
    pack_q_kernel<<<(N * K / 4 + 255) / 256, 256, 0, stream>>>(
        (const int4*)q, (unsigned int*)Qb, N * K / 4);
    // 5. main GEMM + fused epilogue (256x256 tile, 8-phase pipeline)
    gemm_i8_kernel<<<dim3(M / 256, N / 256), 512, 0, stream>>>(
        Xq, Qb, Arow, codes, scales, bias, Pbf, out, M, N, K);
}

// Round 3
// 511.566 us; speedup vs baseline: 1.0214x; 1.0214x over previous
//
#include <hip/hip_runtime.h>

// ---------------------------------------------------------------------------
// BitfieldLinear via rank-structure split:
//   y = r_n * P[m, c_n] + (a_m * s_n/127) * (xq @ qb^T) + bias
//   P = x @ basis^T  (bf16 MFMA, stored bf16 [M,256])
// R8: gemm_i8 8-phase schedule ROLLED: each LDS half-tile re-staged right
//     after its last read -> 7-half-tile-deep pipeline, vmcnt(10) waits with
//     6-7 phases of slack (R6 had only 2-3 phases -> exposed L3/HBM latency).
//     Phases split by M-half (8/4/8/4 ds_reads). Everything else = R6.
// ---------------------------------------------------------------------------

typedef __bf16 bf16x8 __attribute__((ext_vector_type(8)));
typedef float f32x4 __attribute__((ext_vector_type(4)));
typedef int i32x4 __attribute__((ext_vector_type(4)));
typedef unsigned short u16x8 __attribute__((ext_vector_type(8)));

__device__ __forceinline__ unsigned short f2bf(float f) {
    union { float f; unsigned int u; } c; c.f = f;
    unsigned int u = c.u;
    u += 0x7fffu + ((u >> 16) & 1u);
    return (unsigned short)(u >> 16);
}
__device__ __forceinline__ float bf2f(unsigned short h) {
    union { unsigned int u; float f; } c; c.u = ((unsigned int)h) << 16;
    return c.f;
}

__device__ __forceinline__ void load_lds16(const void* g, void* l) {
    __builtin_amdgcn_global_load_lds(
        (__attribute__((address_space(1))) void*)(void*)g,
        (__attribute__((address_space(3))) void*)l,
        16, 0, 0);
}

// r4-verified swizzle for 64-B-row tiles (0 conflicts measured):
// physical 16B-slot p -> (row, chunk) byte offset; 8-slot groups span 2 rows.
__device__ __forceinline__ int swz_decode(int p, int row_bytes) {
    const int g = p >> 3, t = p & 7, v = t ^ (g & 7);
    const int row = g * 2 + (v >> 2), chunk = v & 3;
    return row * row_bytes + chunk * 16;
}

// ---------------- basis fp32 -> bf16 ---------------------------------------
__global__ void cvt_bf16_kernel(const float4* __restrict__ in4,
                                ushort4* __restrict__ out4, int n4) {
    int i = blockIdx.x * blockDim.x + threadIdx.x;
    const int stride = gridDim.x * blockDim.x;
    for (; i < n4; i += stride) {
        float4 v = in4[i];
        ushort4 o;
        o.x = f2bf(v.x); o.y = f2bf(v.y); o.z = f2bf(v.z); o.w = f2bf(v.w);
        out4[i] = o;
    }
}

// ---------------- per-row int8 quantization of x ---------------------------
__global__ void quant_x_kernel(const float* __restrict__ x,
                               signed char* __restrict__ xq,
                               float* __restrict__ arow, int K) {
    const int m = blockIdx.x;
    const float* row = x + (size_t)m * K;
    const int base = threadIdx.x * 16;
    float4 v[4];
#pragma unroll
    for (int j = 0; j < 4; ++j) v[j] = *(const float4*)(row + base + j * 4);

    float lmax = 0.f;
#pragma unroll
    for (int j = 0; j < 4; ++j) {
        lmax = fmaxf(lmax, fabsf(v[j].x));
        lmax = fmaxf(lmax, fabsf(v[j].y));
        lmax = fmaxf(lmax, fabsf(v[j].z));
        lmax = fmaxf(lmax, fabsf(v[j].w));
    }
#pragma unroll
    for (int off = 32; off; off >>= 1)
        lmax = fmaxf(lmax, __shfl_xor(lmax, off));
    __shared__ float smax[4];
    if ((threadIdx.x & 63) == 0) smax[threadIdx.x >> 6] = lmax;
    __syncthreads();
    const float mx = fmaxf(fmaxf(smax[0], smax[1]), fmaxf(smax[2], smax[3]));
    const float inv = mx > 0.f ? 127.0f / mx : 0.0f;
    if (threadIdx.x == 0) arow[m] = mx * (1.0f / 127.0f);

    union { signed char c[16]; i32x4 w; } pk;
#pragma unroll
    for (int j = 0; j < 4; ++j) {
        pk.c[j * 4 + 0] = (signed char)(int)rintf(v[j].x * inv);
        pk.c[j * 4 + 1] = (signed char)(int)rintf(v[j].y * inv);
        pk.c[j * 4 + 2] = (signed char)(int)rintf(v[j].z * inv);
        pk.c[j * 4 + 3] = (signed char)(int)rintf(v[j].w * inv);
    }
    *(i32x4*)(xq + (size_t)m * K + base) = pk.w;
}

// ---------------- pack residual int32 -> int8 (q-128) ----------------------
__global__ void pack_q_kernel(const int4* __restrict__ q4,
                              unsigned int* __restrict__ out, int n4) {
    const int i = blockIdx.x * blockDim.x + threadIdx.x;
    if (i >= n4) return;
    int4 a = q4[i];
    unsigned int w = ((unsigned)(a.x - 128) & 0xFFu)
                   | (((unsigned)(a.y - 128) & 0xFFu) << 8)
                   | (((unsigned)(a.z - 128) & 0xFFu) << 16)
                   | (((unsigned)(a.w - 128) & 0xFFu) << 24);
    out[i] = w;
}

// ---------------- P = x @ basis^T, bf16 out --------------------------------
// Tile: 32 rows (M) x 256 cols (ALL of basis), BK=64. 256 blocks (M/32).
// 512 threads (8 waves, wave = 16 rows x 64 cols), double-buffered
// staging with counted vmcnt(5) so next tile's HBM latency hides under MFMA.
__global__ __launch_bounds__(512) void
p_gemm_kernel(const float* __restrict__ x,           // [M,K] fp32
              const unsigned short* __restrict__ Bb, // [256,K] bf16
              unsigned short* __restrict__ Pbf,      // [M,256] bf16
              int M, int K) {
    __shared__ __align__(16) float As[2][32 * 64];            // 2 x 8 KB
    __shared__ __align__(16) unsigned short Bs[2][256 * 64];  // 2 x 32 KB

    const int tid  = threadIdx.x;
    const int lane = tid & 63;
    const int wv   = tid >> 6;        // 0..7
    const int wr   = wv >> 2;         // 0..1: row half (16 rows)
    const int wc   = wv & 3;          // 0..3: 64-col group
    const int m0 = blockIdx.x * 32;
    const int lr = lane & 15;
    const int kg = lane >> 4;

    f32x4 acc[4];
#pragma unroll
    for (int ni = 0; ni < 4; ++ni) acc[ni] = (f32x4){0.f, 0.f, 0.f, 0.f};

    // A staging: 512 slots (32 rows x 16 chunks of 4 fp32), 1/thread.
    const int aRow = tid >> 4;
    const int aSrc = (tid & 15) ^ (aRow & 15);
    // B staging: 2048 slots (256 rows x 8 chunks of 8 bf16), 4/thread.
    int bRow[4], bSrc[4];
#pragma unroll
    for (int j = 0; j < 4; ++j) {
        const int p = tid + 512 * j;
        bRow[j] = p >> 3;
        bSrc[j] = (p & 7) ^ (bRow[j] & 7);
    }
    const float* aG = x + (size_t)(m0 + aRow) * K + aSrc * 4;
    const unsigned short* bG[4];
#pragma unroll
    for (int j = 0; j < 4; ++j) bG[j] = Bb + (size_t)bRow[j] * K + bSrc[j] * 8;

#define P_STAGE(bb, k0)                                                        \
    do {                                                                       \
        load_lds16(aG + (k0), (char*)As[bb] + tid * 16);                       \
        _Pragma("unroll") for (int j = 0; j < 4; ++j)                          \
            load_lds16(bG[j] + (k0), (char*)Bs[bb] + (tid + 512 * j) * 16);    \
    } while (0)

    P_STAGE(0, 0);
    const int NT = K >> 6;
    for (int t = 0; t < NT; ++t) {
        const int bb = t & 1;
        if (t + 1 < NT) {
            P_STAGE(bb ^ 1, (t + 1) << 6);
            asm volatile("s_waitcnt vmcnt(5)" ::: "memory");  // tile t resident
        } else {
            asm volatile("s_waitcnt vmcnt(0)" ::: "memory");
        }
        __builtin_amdgcn_s_barrier();

        const float* Ab = As[bb];
        const unsigned short* Bbf = Bs[bb];
#pragma unroll
        for (int s = 0; s < 2; ++s) {
            const int r = wr * 16 + lr;
            const int c0 = s * 8 + kg * 2;
            const int ph0 = c0 ^ (r & 15);
            const int ph1 = (c0 + 1) ^ (r & 15);
            f32x4 lo = *(const f32x4*)(Ab + r * 64 + ph0 * 4);
            f32x4 hi = *(const f32x4*)(Ab + r * 64 + ph1 * 4);
            bf16x8 a;
            a[0] = (__bf16)lo[0]; a[1] = (__bf16)lo[1];
            a[2] = (__bf16)lo[2]; a[3] = (__bf16)lo[3];
            a[4] = (__bf16)hi[0]; a[5] = (__bf16)hi[1];
            a[6] = (__bf16)hi[2]; a[7] = (__bf16)hi[3];
#pragma unroll
            for (int ni = 0; ni < 4; ++ni) {
                const int rb = wc * 64 + ni * 16 + lr;
                const int ph = (s * 4 + kg) ^ (rb & 7);
                bf16x8 bfr = __builtin_bit_cast(bf16x8,
                    *(const u16x8*)(Bbf + rb * 64 + ph * 8));
                acc[ni] = __builtin_amdgcn_mfma_f32_16x16x32_bf16(
                    a, bfr, acc[ni], 0, 0, 0);
            }
        }
        __builtin_amdgcn_s_barrier();
    }
#undef P_STAGE

#pragma unroll
    for (int ni = 0; ni < 4; ++ni) {
        const int n = wc * 64 + ni * 16 + lr;
        const int mb = m0 + wr * 16 + kg * 4;
#pragma unroll
        for (int rg = 0; rg < 4; ++rg)
            Pbf[(size_t)(mb + rg) * 256 + n] = f2bf(acc[ni][rg]);
    }
}

// ---------------- main i8 GEMM + fused epilogue ----------------------------
// 256(M) x 256(N) tile, BK=128, 8 waves (2Mx4N, wave = 128 x 64).
// Rolled 8-phase schedule (per K-tile: 4 phases = M-half x K-half, 16 MFMA
// each). Each phase stages the ONE half-tile whose LDS region was freed in
// the previous phase -> 7 half-tiles (14 loads) in flight; vmcnt(10) at
// P2/P4 drains half-tiles issued 6-7 phases earlier (latency fully hidden).
// Region map per 64KB buffer: A_ks0 [0,16K) A_ks1 [16K,32K)
//                             B_ks0 [32K,48K) B_ks1 [48K,64K)
// Stage plan, iter t: P1->A1(t+1)[nbuf]  P2->B0(t+2)[buf]
//                     P3->A0(t+2)[buf]   P4->B1(t+2)[buf]
// (each region is written only after its last reader drained + barrier).
__global__ __launch_bounds__(512, 2) void
gemm_i8_kernel(const signed char* __restrict__ Xq, // [M,K]
               const signed char* __restrict__ Qb, // [N,K]
               const float* __restrict__ arow,     // [M]
               const int* __restrict__ codes,      // [N]
               const float* __restrict__ scales,   // [N]
               const float* __restrict__ bias,     // [N]
               const unsigned short* __restrict__ Pbf, // [M,256] bf16
               float* __restrict__ out,            // [M,N]
               int M, int N, int K) {
    __shared__ __align__(16) signed char lds[2 * 65536];  // 128 KB

    const int tid  = threadIdx.x;
    const int lane = tid & 63;
    const int wv   = tid >> 6;
    const int wr   = wv >> 2;         // 0..1 (128-row half)
    const int wc   = wv & 3;          // 0..3 (64-col quarter)
    const int m0 = blockIdx.x * 256;
    const int n0 = blockIdx.y * 256;
    const int lr = lane & 15;
    const int kg = lane >> 4;
    const int cidx = (((lr & 1) << 2) | kg) ^ ((lr >> 1) & 7);

    // staging: each 16KB sub-region = 1024 slots of 16B (256 rows x 64B).
    // Thread covers slots tid and tid+512; source pre-swizzled (r4 pattern).
    const int o0 = swz_decode(tid, 64);
    const int o1 = swz_decode(tid + 512, 64);
    const signed char* aG0 = Xq + (size_t)(m0 + (o0 >> 6)) * K + (o0 & 63);
    const signed char* aG1 = Xq + (size_t)(m0 + (o1 >> 6)) * K + (o1 & 63);
    const signed char* bG0 = Qb + (size_t)(n0 + (o0 >> 6)) * K + (o0 & 63);
    const signed char* bG1 = Qb + (size_t)(n0 + (o1 >> 6)) * K + (o1 & 63);
    const int d0 = tid * 16;
    const int d1 = d0 + 8192;

    i32x4 acc[8][4];
#pragma unroll
    for (int mi = 0; mi < 8; ++mi)
#pragma unroll
        for (int ni = 0; ni < 4; ++ni)
            acc[mi][ni] = (i32x4){0, 0, 0, 0};

    // LDS fragment read bases (r4-swizzle conflict-free pattern):
    // A frag (mi,ks): buf + ks*16384 + raBase + mi*1024
    // B frag (ni,ks): buf + ks*16384 + rbBase + ni*1024   (rbBase incl +32768)
    const int raBase = (wr * 64 + (lr >> 1)) * 128 + cidx * 16;
    const int rbBase = 32768 + (wc * 32 + (lr >> 1)) * 128 + cidx * 16;

#define STG_A(bufo, ks, kb)                                                    \
    do {                                                                       \
        load_lds16(aG0 + (kb) + (ks) * 64, lds + (bufo) + (ks) * 16384 + d0);  \
        load_lds16(aG1 + (kb) + (ks) * 64, lds + (bufo) + (ks) * 16384 + d1);  \
    } while (0)
#define STG_B(bufo, ks, kb)                                                    \
    do {                                                                       \
        load_lds16(bG0 + (kb) + (ks) * 64,                                     \
                   lds + (bufo) + 32768 + (ks) * 16384 + d0);                  \
        load_lds16(bG1 + (kb) + (ks) * 64,                                     \
                   lds + (bufo) + 32768 + (ks) * 16384 + d1);                  \
    } while (0)

    const int NT = K >> 7;  // BK=128; requires NT >= 2 (K=4096 -> 32)

    // Prologue — issue in steady-state age order:
    // B0(0),A0(0),B1(0),A1(0),B0(1),A0(1),B1(1)  = 7 half-tiles, 14 loads.
    STG_B(0, 0, 0);       STG_A(0, 0, 0);
    STG_B(0, 1, 0);       STG_A(0, 1, 0);
    STG_B(65536, 0, 128); STG_A(65536, 0, 128);
    STG_B(65536, 1, 128);
    asm volatile("s_waitcnt vmcnt(10)" ::: "memory");  // drain B0(0),A0(0)
    __builtin_amdgcn_s_barrier();

#pragma unroll 2
    for (int t = 0; t < NT; ++t) {
        const int buf  = (t & 1) << 16;
        const int nbuf = buf ^ 65536;
        const int kb1 = ((t + 1 < NT) ? t + 1 : NT - 1) << 7;  // clamped tail
        const int kb2 = ((t + 2 < NT) ? t + 2 : NT - 1) << 7;
        i32x4 a[4], b[4];

        // ---- P1: ks0, mi 0..3 (+ all 4 B ks0 frags) ----
#pragma unroll
        for (int mi = 0; mi < 4; ++mi)
            a[mi] = *(const i32x4*)(lds + buf + raBase + mi * 1024);
#pragma unroll
        for (int ni = 0; ni < 4; ++ni)
            b[ni] = *(const i32x4*)(lds + buf + rbBase + ni * 1024);
        STG_A(nbuf, 1, kb1);                    // A1(t+1)
        __builtin_amdgcn_s_barrier();
        asm volatile("s_waitcnt lgkmcnt(0)" ::: "memory");
        __builtin_amdgcn_s_setprio(1);
#pragma unroll
        for (int ni = 0; ni < 4; ++ni)
#pragma unroll
            for (int mi = 0; mi < 4; ++mi)
                acc[mi][ni] = __builtin_amdgcn_mfma_i32_16x16x64_i8(
                    a[mi], b[ni], acc[mi][ni], 0, 0, 0);
        __builtin_amdgcn_s_setprio(0);
        __builtin_amdgcn_s_barrier();

        // ---- P2: ks0, mi 4..7 (B held in regs) ----
#pragma unroll
        for (int mi = 0; mi < 4; ++mi)
            a[mi] = *(const i32x4*)(lds + buf + raBase + (mi + 4) * 1024);
        STG_B(buf, 0, kb2);                     // B0(t+2)
        __builtin_amdgcn_s_barrier();
        asm volatile("s_waitcnt lgkmcnt(0)" ::: "memory");
        __builtin_amdgcn_s_setprio(1);
#pragma unroll
        for (int ni = 0; ni < 4; ++ni)
#pragma unroll
            for (int mi = 0; mi < 4; ++mi)
                acc[mi + 4][ni] = __builtin_amdgcn_mfma_i32_16x16x64_i8(
                    a[mi], b[ni], acc[mi + 4][ni], 0, 0, 0);
        __builtin_amdgcn_s_setprio(0);
        asm volatile("s_waitcnt vmcnt(10)" ::: "memory");  // drain B1(t),A1(t)
        __builtin_amdgcn_s_barrier();

        // ---- P3: ks1, mi 0..3 (+ all 4 B ks1 frags) ----
#pragma unroll
        for (int mi = 0; mi < 4; ++mi)
            a[mi] = *(const i32x4*)(lds + buf + 16384 + raBase + mi * 1024);
#pragma unroll
        for (int ni = 0; ni < 4; ++ni)
            b[ni] = *(const i32x4*)(lds + buf + 16384 + rbBase + ni * 1024);
        STG_A(buf, 0, kb2);                     // A0(t+2)
        __builtin_amdgcn_s_barrier();
        asm volatile("s_waitcnt lgkmcnt(0)" ::: "memory");
        __builtin_amdgcn_s_setprio(1);
#pragma unroll
        for (int ni = 0; ni < 4; ++ni)
#pragma unroll
            for (int mi = 0; mi < 4; ++mi)
                acc[mi][ni] = __builtin_amdgcn_mfma_i32_16x16x64_i8(
                    a[mi], b[ni], acc[mi][ni], 0, 0, 0);
        __builtin_amdgcn_s_setprio(0);
        __builtin_amdgcn_s_barrier();

        // ---- P4: ks1, mi 4..7 (B held in regs) ----
#pragma unroll
        for (int mi = 0; mi < 4; ++mi)
            a[mi] = *(const i32x4*)(lds + buf + 16384 + raBase + (mi + 4) * 1024);
        STG_B(buf, 1, kb2);                     // B1(t+2)
        __builtin_amdgcn_s_barrier();
        asm volatile("s_waitcnt lgkmcnt(0)" ::: "memory");
        __builtin_amdgcn_s_setprio(1);
#pragma unroll
        for (int ni = 0; ni < 4; ++ni)
#pragma unroll
            for (int mi = 0; mi < 4; ++mi)
                acc[mi + 4][ni] = __builtin_amdgcn_mfma_i32_16x16x64_i8(
                    a[mi], b[ni], acc[mi + 4][ni], 0, 0, 0);
        __builtin_amdgcn_s_setprio(0);
        asm volatile("s_waitcnt vmcnt(10)" ::: "memory");  // drain B0(t+1),A0(t+1)
        __builtin_amdgcn_s_barrier();
    }
#undef STG_A
#undef STG_B
    asm volatile("s_waitcnt vmcnt(0)" ::: "memory");  // drain tail stages

    // ---- epilogue: per-row x scales, per-col decode, P gather, NT store ---
    const int mwb = m0 + wr * 128 + kg * 4;
    float av[8][4];
#pragma unroll
    for (int mi = 0; mi < 8; ++mi)
#pragma unroll
        for (int rg = 0; rg < 4; ++rg)
            av[mi][rg] = arow[mwb + mi * 16 + rg];

#pragma unroll
    for (int ni = 0; ni < 4; ++ni) {
        const int n = n0 + wc * 64 + ni * 16 + lr;
        const int code = codes[n];
        const int cc = code & 0xFF;
        const float rr = (float)((code >> 8) & 0xFFFF) * (1.0f / 65535.0f);
        const float so = scales[n] * (1.0f / 127.0f);
        const float bv = bias[n];
#pragma unroll
        for (int mi = 0; mi < 8; ++mi) {
            const int mbase = mwb + mi * 16;
            unsigned short pv[4];
#pragma unroll
            for (int rg = 0; rg < 4; ++rg)
                pv[rg] = Pbf[(size_t)(mbase + rg) * 256 + cc];
#pragma unroll
            for (int rg = 0; rg < 4; ++rg) {
                const float y = av[mi][rg] * so * (float)acc[mi][ni][rg]
                              + rr * bf2f(pv[rg]) + bv;
                __builtin_nontemporal_store(y, &out[(size_t)(mbase + rg) * N + n]);
            }
        }
    }
}

// ---------------------------------------------------------------------------
extern "C" void kernel_launch(void* const* d_in, const int* in_sizes, int n_in,
                              void* d_out, int out_size, void* d_ws, size_t ws_size,
                              hipStream_t stream) {
    const float* x        = (const float*)d_in[0];
    const int*   codes    = (const int*)d_in[1];
    const float* basis    = (const float*)d_in[2];
    const int*   q        = (const int*)d_in[3];
    const float* scales   = (const float*)d_in[4];
    const float* bias     = (const float*)d_in[5];
    float* out = (float*)d_out;

    const int BASIS = 256;
    const int K = in_sizes[2] / BASIS;   // 4096
    const int N = in_sizes[1];           // 4096
    const int M = in_sizes[0] / K;       // 8192

    char* ws = (char*)d_ws;
    signed char* Xq = (signed char*)ws;                  // [M,K] i8, 33.5 MB
    size_t off = (size_t)M * K;
    signed char* Qb = (signed char*)(ws + off);          // [N,K] i8, 16.7 MB
    off += (size_t)N * K;
    unsigned short* Pbf = (unsigned short*)(ws + off);   // [M,256] bf16, 4 MB
    off += (size_t)M * 256 * 2;
    float* Arow = (float*)(ws + off);                    // [M] fp32
    off += (size_t)M * sizeof(float);
    unsigned short* Bb = (unsigned short*)(ws + off);    // [256,K] bf16, 2 MB

    // 1. basis -> bf16 (2 MB)
    cvt_bf16_kernel<<<1024, 256, 0, stream>>>((const float4*)basis, (ushort4*)Bb,
                                              BASIS * K / 4);
    // 2. P = x @ basis^T  (reads x fp32 directly)
    p_gemm_kernel<<<M / 32, 512, 0, stream>>>(x, Bb, Pbf, M, K);
    // 3. x -> i8 + per-row scale
    quant_x_kernel<<<M, 256, 0, stream>>>(x, Xq, Arow, K);
    // 4. residual -> i8
    pack_q_kernel<<<(N * K / 4 + 255) / 256, 256, 0, stream>>>(
        (const int4*)q, (unsigned int*)Qb, N * K / 4);
    // 5. main GEMM + fused epilogue (256x256 tile, rolled 8-phase pipeline)
    gemm_i8_kernel<<<dim3(M / 256, N / 256), 512, 0, stream>>>(
        Xq, Qb, Arow, codes, scales, bias, Pbf, out, M, N, K);
}

// Round 4
// 493.040 us; speedup vs baseline: 1.0598x; 1.0376x over previous
//
#include <hip/hip_runtime.h>

// ---------------------------------------------------------------------------
// BitfieldLinear via rank-structure split:
//   y = r_n * P[m, c_n] + (a_m * s_n/127) * (xq @ qb^T) + bias
//   P = x @ basis^T  (bf16 MFMA, stored bf16 [M,256])
// R9: gemm_i8 reverted to the R5-verified 128x256/BK=64/2-blocks-per-CU
//     geometry, upgraded with a 2-deep LDS double-buffer prefetch:
//     STAGE(t+1) issued BEFORE compute(t); vmcnt(0) drain moved to END of
//     compute so ~1300 cyc of MFMA covers the L2/HBM latency (R5 exposed it
//     every K-tile). 48 KB LDS -> still 2 blocks/CU (96 KB).
//     R6/R8's 256^2 1-block/CU experiments regressed (no cross-block cover).
// ---------------------------------------------------------------------------

typedef __bf16 bf16x8 __attribute__((ext_vector_type(8)));
typedef float f32x4 __attribute__((ext_vector_type(4)));
typedef int i32x4 __attribute__((ext_vector_type(4)));
typedef unsigned short u16x8 __attribute__((ext_vector_type(8)));

__device__ __forceinline__ unsigned short f2bf(float f) {
    union { float f; unsigned int u; } c; c.f = f;
    unsigned int u = c.u;
    u += 0x7fffu + ((u >> 16) & 1u);
    return (unsigned short)(u >> 16);
}
__device__ __forceinline__ float bf2f(unsigned short h) {
    union { unsigned int u; float f; } c; c.u = ((unsigned int)h) << 16;
    return c.f;
}

__device__ __forceinline__ void load_lds16(const void* g, void* l) {
    __builtin_amdgcn_global_load_lds(
        (__attribute__((address_space(1))) void*)(void*)g,
        (__attribute__((address_space(3))) void*)l,
        16, 0, 0);
}

// r4-verified swizzle for 64-B-row tiles (0 conflicts measured):
// physical 16B-slot p -> (row, chunk) byte offset; 8-slot groups span 2 rows.
__device__ __forceinline__ int swz_decode(int p, int row_bytes) {
    const int g = p >> 3, t = p & 7, v = t ^ (g & 7);
    const int row = g * 2 + (v >> 2), chunk = v & 3;
    return row * row_bytes + chunk * 16;
}

// ---------------- basis fp32 -> bf16 ---------------------------------------
__global__ void cvt_bf16_kernel(const float4* __restrict__ in4,
                                ushort4* __restrict__ out4, int n4) {
    int i = blockIdx.x * blockDim.x + threadIdx.x;
    const int stride = gridDim.x * blockDim.x;
    for (; i < n4; i += stride) {
        float4 v = in4[i];
        ushort4 o;
        o.x = f2bf(v.x); o.y = f2bf(v.y); o.z = f2bf(v.z); o.w = f2bf(v.w);
        out4[i] = o;
    }
}

// ---------------- per-row int8 quantization of x ---------------------------
__global__ void quant_x_kernel(const float* __restrict__ x,
                               signed char* __restrict__ xq,
                               float* __restrict__ arow, int K) {
    const int m = blockIdx.x;
    const float* row = x + (size_t)m * K;
    const int base = threadIdx.x * 16;
    float4 v[4];
#pragma unroll
    for (int j = 0; j < 4; ++j) v[j] = *(const float4*)(row + base + j * 4);

    float lmax = 0.f;
#pragma unroll
    for (int j = 0; j < 4; ++j) {
        lmax = fmaxf(lmax, fabsf(v[j].x));
        lmax = fmaxf(lmax, fabsf(v[j].y));
        lmax = fmaxf(lmax, fabsf(v[j].z));
        lmax = fmaxf(lmax, fabsf(v[j].w));
    }
#pragma unroll
    for (int off = 32; off; off >>= 1)
        lmax = fmaxf(lmax, __shfl_xor(lmax, off));
    __shared__ float smax[4];
    if ((threadIdx.x & 63) == 0) smax[threadIdx.x >> 6] = lmax;
    __syncthreads();
    const float mx = fmaxf(fmaxf(smax[0], smax[1]), fmaxf(smax[2], smax[3]));
    const float inv = mx > 0.f ? 127.0f / mx : 0.0f;
    if (threadIdx.x == 0) arow[m] = mx * (1.0f / 127.0f);

    union { signed char c[16]; i32x4 w; } pk;
#pragma unroll
    for (int j = 0; j < 4; ++j) {
        pk.c[j * 4 + 0] = (signed char)(int)rintf(v[j].x * inv);
        pk.c[j * 4 + 1] = (signed char)(int)rintf(v[j].y * inv);
        pk.c[j * 4 + 2] = (signed char)(int)rintf(v[j].z * inv);
        pk.c[j * 4 + 3] = (signed char)(int)rintf(v[j].w * inv);
    }
    *(i32x4*)(xq + (size_t)m * K + base) = pk.w;
}

// ---------------- pack residual int32 -> int8 (q-128) ----------------------
__global__ void pack_q_kernel(const int4* __restrict__ q4,
                              unsigned int* __restrict__ out, int n4) {
    const int i = blockIdx.x * blockDim.x + threadIdx.x;
    if (i >= n4) return;
    int4 a = q4[i];
    unsigned int w = ((unsigned)(a.x - 128) & 0xFFu)
                   | (((unsigned)(a.y - 128) & 0xFFu) << 8)
                   | (((unsigned)(a.z - 128) & 0xFFu) << 16)
                   | (((unsigned)(a.w - 128) & 0xFFu) << 24);
    out[i] = w;
}

// ---------------- P = x @ basis^T, bf16 out --------------------------------
// Tile: 32 rows (M) x 256 cols (ALL of basis), BK=64. 256 blocks (M/32).
// 512 threads (8 waves, wave = 16 rows x 64 cols), double-buffered
// staging with counted vmcnt(5) so next tile's HBM latency hides under MFMA.
__global__ __launch_bounds__(512) void
p_gemm_kernel(const float* __restrict__ x,           // [M,K] fp32
              const unsigned short* __restrict__ Bb, // [256,K] bf16
              unsigned short* __restrict__ Pbf,      // [M,256] bf16
              int M, int K) {
    __shared__ __align__(16) float As[2][32 * 64];            // 2 x 8 KB
    __shared__ __align__(16) unsigned short Bs[2][256 * 64];  // 2 x 32 KB

    const int tid  = threadIdx.x;
    const int lane = tid & 63;
    const int wv   = tid >> 6;        // 0..7
    const int wr   = wv >> 2;         // 0..1: row half (16 rows)
    const int wc   = wv & 3;          // 0..3: 64-col group
    const int m0 = blockIdx.x * 32;
    const int lr = lane & 15;
    const int kg = lane >> 4;

    f32x4 acc[4];
#pragma unroll
    for (int ni = 0; ni < 4; ++ni) acc[ni] = (f32x4){0.f, 0.f, 0.f, 0.f};

    // A staging: 512 slots (32 rows x 16 chunks of 4 fp32), 1/thread.
    const int aRow = tid >> 4;
    const int aSrc = (tid & 15) ^ (aRow & 15);
    // B staging: 2048 slots (256 rows x 8 chunks of 8 bf16), 4/thread.
    int bRow[4], bSrc[4];
#pragma unroll
    for (int j = 0; j < 4; ++j) {
        const int p = tid + 512 * j;
        bRow[j] = p >> 3;
        bSrc[j] = (p & 7) ^ (bRow[j] & 7);
    }
    const float* aG = x + (size_t)(m0 + aRow) * K + aSrc * 4;
    const unsigned short* bG[4];
#pragma unroll
    for (int j = 0; j < 4; ++j) bG[j] = Bb + (size_t)bRow[j] * K + bSrc[j] * 8;

#define P_STAGE(bb, k0)                                                        \
    do {                                                                       \
        load_lds16(aG + (k0), (char*)As[bb] + tid * 16);                       \
        _Pragma("unroll") for (int j = 0; j < 4; ++j)                          \
            load_lds16(bG[j] + (k0), (char*)Bs[bb] + (tid + 512 * j) * 16);    \
    } while (0)

    P_STAGE(0, 0);
    const int NT = K >> 6;
    for (int t = 0; t < NT; ++t) {
        const int bb = t & 1;
        if (t + 1 < NT) {
            P_STAGE(bb ^ 1, (t + 1) << 6);
            asm volatile("s_waitcnt vmcnt(5)" ::: "memory");  // tile t resident
        } else {
            asm volatile("s_waitcnt vmcnt(0)" ::: "memory");
        }
        __builtin_amdgcn_s_barrier();

        const float* Ab = As[bb];
        const unsigned short* Bbf = Bs[bb];
#pragma unroll
        for (int s = 0; s < 2; ++s) {
            const int r = wr * 16 + lr;
            const int c0 = s * 8 + kg * 2;
            const int ph0 = c0 ^ (r & 15);
            const int ph1 = (c0 + 1) ^ (r & 15);
            f32x4 lo = *(const f32x4*)(Ab + r * 64 + ph0 * 4);
            f32x4 hi = *(const f32x4*)(Ab + r * 64 + ph1 * 4);
            bf16x8 a;
            a[0] = (__bf16)lo[0]; a[1] = (__bf16)lo[1];
            a[2] = (__bf16)lo[2]; a[3] = (__bf16)lo[3];
            a[4] = (__bf16)hi[0]; a[5] = (__bf16)hi[1];
            a[6] = (__bf16)hi[2]; a[7] = (__bf16)hi[3];
#pragma unroll
            for (int ni = 0; ni < 4; ++ni) {
                const int rb = wc * 64 + ni * 16 + lr;
                const int ph = (s * 4 + kg) ^ (rb & 7);
                bf16x8 bfr = __builtin_bit_cast(bf16x8,
                    *(const u16x8*)(Bbf + rb * 64 + ph * 8));
                acc[ni] = __builtin_amdgcn_mfma_f32_16x16x32_bf16(
                    a, bfr, acc[ni], 0, 0, 0);
            }
        }
        __builtin_amdgcn_s_barrier();
    }
#undef P_STAGE

#pragma unroll
    for (int ni = 0; ni < 4; ++ni) {
        const int n = wc * 64 + ni * 16 + lr;
        const int mb = m0 + wr * 16 + kg * 4;
#pragma unroll
        for (int rg = 0; rg < 4; ++rg)
            Pbf[(size_t)(mb + rg) * 256 + n] = f2bf(acc[ni][rg]);
    }
}

// ---------------- main i8 GEMM + fused epilogue ----------------------------
// R5-verified geometry: 128(M) x 256(N) tile, BK=64, 4 waves 2x2;
// wave = 64 rows x 128 cols (af[4], bfr[8], acc[4][8]). r4 swizzle, epilogue
// P gather, NT stores. R9 adds a 2-deep double buffer: STAGE(t+1) issued at
// top of iter t, vmcnt(0) drain at END of compute(t) (covered by ~1300 cyc
// of ds_read+MFMA). 48 KB LDS -> 2 blocks/CU preserved.
__global__ __launch_bounds__(256, 2) void
gemm_i8_kernel(const signed char* __restrict__ Xq, // [M,K]
               const signed char* __restrict__ Qb, // [N,K]
               const float* __restrict__ arow,     // [M]
               const int* __restrict__ codes,      // [N]
               const float* __restrict__ scales,   // [N]
               const float* __restrict__ bias,     // [N]
               const unsigned short* __restrict__ Pbf, // [M,256] bf16
               float* __restrict__ out,            // [M,N]
               int M, int N, int K) {
    __shared__ __align__(16) signed char As[2][128 * 64];  // 2 x 8 KB
    __shared__ __align__(16) signed char Bs[2][256 * 64];  // 2 x 16 KB

    const int tid  = threadIdx.x;
    const int lane = tid & 63;
    const int wv   = tid >> 6;
    const int wr   = wv >> 1;         // 0..1 (row half)
    const int wc   = wv & 1;          // 0..1 (col half)
    const int m0 = blockIdx.x * 128;  // m-major grid: consecutive blocks share n0
    const int n0 = blockIdx.y * 256;
    const int lr = lane & 15;
    const int kg = lane >> 4;
    const int cidx = (((lr & 1) << 2) | kg) ^ ((lr >> 1) & 7);

    i32x4 acc[4][8];
#pragma unroll
    for (int mi = 0; mi < 4; ++mi)
#pragma unroll
        for (int ni = 0; ni < 8; ++ni)
            acc[mi][ni] = (i32x4){0, 0, 0, 0};

    // A: 512 slots (2/thread); B: 1024 slots (4/thread). 64-B rows, r4 swizzle.
    int gaOff[2], gbOff[4];
#pragma unroll
    for (int j = 0; j < 2; ++j) gaOff[j] = swz_decode(tid + 256 * j, 64);
#pragma unroll
    for (int j = 0; j < 4; ++j) gbOff[j] = swz_decode(tid + 256 * j, 64);

    const signed char* aSrc[2];
    const signed char* bSrc[4];
#pragma unroll
    for (int j = 0; j < 2; ++j)
        aSrc[j] = Xq + (size_t)(m0 + (gaOff[j] >> 6)) * K + (gaOff[j] & 63);
#pragma unroll
    for (int j = 0; j < 4; ++j)
        bSrc[j] = Qb + (size_t)(n0 + (gbOff[j] >> 6)) * K + (gbOff[j] & 63);

#define G_STAGE(bb, k0)                                                        \
    do {                                                                       \
        _Pragma("unroll") for (int j = 0; j < 2; ++j)                          \
            load_lds16(aSrc[j] + (k0), (char*)As[bb] + (tid + 256 * j) * 16);  \
        _Pragma("unroll") for (int j = 0; j < 4; ++j)                          \
            load_lds16(bSrc[j] + (k0), (char*)Bs[bb] + (tid + 256 * j) * 16);  \
    } while (0)

    // Prologue: stage tile 0, drain, sync.
    G_STAGE(0, 0);
    asm volatile("s_waitcnt vmcnt(0)" ::: "memory");
    __builtin_amdgcn_s_barrier();

    const int NT = K >> 6;
#pragma unroll 2
    for (int t = 0; t < NT; ++t) {
        const int bb = t & 1;
        // Prefetch next tile into the other buffer (WAR closed by the
        // barrier at end of iter t-1: all reads of buf bb^1 drained there).
        if (t + 1 < NT) G_STAGE(bb ^ 1, (t + 1) << 6);

        // Compute on buffer bb (~1300 cyc/CU) — covers prefetch latency.
        i32x4 af[4], bfr[8];
#pragma unroll
        for (int mi = 0; mi < 4; ++mi) {
            const int r2 = wr * 32 + mi * 8 + (lr >> 1);
            af[mi] = *(const i32x4*)(As[bb] + r2 * 128 + cidx * 16);
        }
#pragma unroll
        for (int ni = 0; ni < 8; ++ni) {
            const int r2 = wc * 64 + ni * 8 + (lr >> 1);
            bfr[ni] = *(const i32x4*)(Bs[bb] + r2 * 128 + cidx * 16);
        }
#pragma unroll
        for (int mi = 0; mi < 4; ++mi)
#pragma unroll
            for (int ni = 0; ni < 8; ++ni)
                acc[mi][ni] = __builtin_amdgcn_mfma_i32_16x16x64_i8(
                    af[mi], bfr[ni], acc[mi][ni], 0, 0, 0);

        // Drain prefetch (mostly complete by now) + sync before flip.
        asm volatile("s_waitcnt vmcnt(0)" ::: "memory");
        __builtin_amdgcn_s_barrier();
    }
#undef G_STAGE

    // ---- epilogue: per-row x scales, per-col decode, P gather, NT store ---
    float av[4][4];
#pragma unroll
    for (int mi = 0; mi < 4; ++mi)
#pragma unroll
        for (int rg = 0; rg < 4; ++rg)
            av[mi][rg] = arow[m0 + wr * 64 + mi * 16 + kg * 4 + rg];

#pragma unroll
    for (int ni = 0; ni < 8; ++ni) {
        const int n = n0 + wc * 128 + ni * 16 + lr;
        const int code = codes[n];
        const int cc = code & 0xFF;
        const float rr = (float)((code >> 8) & 0xFFFF) * (1.0f / 65535.0f);
        const float so = scales[n] * (1.0f / 127.0f);
        const float bv = bias[n];
#pragma unroll
        for (int mi = 0; mi < 4; ++mi) {
            const int mbase = m0 + wr * 64 + mi * 16 + kg * 4;
            unsigned short pv[4];
#pragma unroll
            for (int rg = 0; rg < 4; ++rg)
                pv[rg] = Pbf[(size_t)(mbase + rg) * 256 + cc];
#pragma unroll
            for (int rg = 0; rg < 4; ++rg) {
                const float y = av[mi][rg] * so * (float)acc[mi][ni][rg]
                              + rr * bf2f(pv[rg]) + bv;
                __builtin_nontemporal_store(y, &out[(size_t)(mbase + rg) * N + n]);
            }
        }
    }
}

// ---------------------------------------------------------------------------
extern "C" void kernel_launch(void* const* d_in, const int* in_sizes, int n_in,
                              void* d_out, int out_size, void* d_ws, size_t ws_size,
                              hipStream_t stream) {
    const float* x        = (const float*)d_in[0];
    const int*   codes    = (const int*)d_in[1];
    const float* basis    = (const float*)d_in[2];
    const int*   q        = (const int*)d_in[3];
    const float* scales   = (const float*)d_in[4];
    const float* bias     = (const float*)d_in[5];
    float* out = (float*)d_out;

    const int BASIS = 256;
    const int K = in_sizes[2] / BASIS;   // 4096
    const int N = in_sizes[1];           // 4096
    const int M = in_sizes[0] / K;       // 8192

    char* ws = (char*)d_ws;
    signed char* Xq = (signed char*)ws;                  // [M,K] i8, 33.5 MB
    size_t off = (size_t)M * K;
    signed char* Qb = (signed char*)(ws + off);          // [N,K] i8, 16.7 MB
    off += (size_t)N * K;
    unsigned short* Pbf = (unsigned short*)(ws + off);   // [M,256] bf16, 4 MB
    off += (size_t)M * 256 * 2;
    float* Arow = (float*)(ws + off);                    // [M] fp32
    off += (size_t)M * sizeof(float);
    unsigned short* Bb = (unsigned short*)(ws + off);    // [256,K] bf16, 2 MB

    // 1. basis -> bf16 (2 MB)
    cvt_bf16_kernel<<<1024, 256, 0, stream>>>((const float4*)basis, (ushort4*)Bb,
                                              BASIS * K / 4);
    // 2. P = x @ basis^T  (reads x fp32 directly)
    p_gemm_kernel<<<M / 32, 512, 0, stream>>>(x, Bb, Pbf, M, K);
    // 3. x -> i8 + per-row scale
    quant_x_kernel<<<M, 256, 0, stream>>>(x, Xq, Arow, K);
    // 4. residual -> i8
    pack_q_kernel<<<(N * K / 4 + 255) / 256, 256, 0, stream>>>(
        (const int4*)q, (unsigned int*)Qb, N * K / 4);
    // 5. main GEMM + fused epilogue (128x256 tile, 2-deep prefetch)
    gemm_i8_kernel<<<dim3(M / 128, N / 256), 256, 0, stream>>>(
        Xq, Qb, Arow, codes, scales, bias, Pbf, out, M, N, K);
}